// Round 13
// baseline (141.406 us; speedup 1.0000x reference)
//
#include <hip/hip_runtime.h>
#include <hip/hip_bf16.h>

// GAT: N=4096 nodes, IN_F=256, H=4 heads, D=64.
// K0 gat_pack : blocks [0,4096): adj row -> 256-bit-packed row (gl16 LDS staging).
//               blocks [4096,4112): W (fp32 [k][c]) -> WT bf16 [c][k] (128 KB).
//               blocks [4112,4368): x (fp32) -> xb bf16 row-major (2 MB).
// K1 gat_prep : h = xb@W via mfma_16x16x32_bf16 (fp32 acc). 64-row x 64-col blocks;
//               A/B fragments staged full-K into LDS with per-lane-gather gl16 in
//               MFMA lane order. si/sj fp32 from acc; hTf bf16 fragment-major.
// K2 gat_attn : masked softmax + PV via MFMA. 32-row tiles x 4 heads, NO j-split:
//               16 double-buffered 256-j windows cover all j; l complete per block
//               -> normalize + write out directly (no reduce kernel).

typedef __bf16 bf16x8 __attribute__((ext_vector_type(8)));
typedef __bf16 bf16x4 __attribute__((ext_vector_type(4)));
typedef float floatx4 __attribute__((ext_vector_type(4)));

#define LOG2E 1.4426950408889634f
#define NN 4096

__device__ __forceinline__ void gl16(const void* g, void* l) {
  __builtin_amdgcn_global_load_lds(
      (const __attribute__((address_space(1))) unsigned int*)g,
      (__attribute__((address_space(3))) unsigned int*)l, 16, 0, 0);
}

// ---------------- Kernel 0: pack + dtype conversions ----------------
__global__ __launch_bounds__(256) void gat_pack(
    const int* __restrict__ adj, const float* __restrict__ x,
    const float* __restrict__ W, unsigned short* __restrict__ adjm,
    __bf16* __restrict__ xb, __bf16* __restrict__ WT) {
  __shared__ __align__(16) int buf[4096];   // 16 KB
  const int b = blockIdx.x, t = threadIdx.x;
  const int w = t >> 6, lane = t & 63;

  if (b < 4096) {  // ---- adj row b -> 256-bit mask row ----
    const int* sp = adj + (size_t)b * 4096 + w * 1024 + lane * 4;
    int* dp = buf + w * 1024 + lane * 4;
#pragma unroll
    for (int r = 0; r < 4; ++r) gl16(sp + r * 256, dp + r * 256);
    __syncthreads();   // drain gl16 -> buf valid
    const int4* rp = (const int4*)(buf + t * 16);
    int4 v0 = rp[0], v1 = rp[1], v2 = rp[2], v3 = rp[3];
    int vs[16] = {v0.x, v0.y, v0.z, v0.w, v1.x, v1.y, v1.z, v1.w,
                  v2.x, v2.y, v2.z, v2.w, v3.x, v3.y, v3.z, v3.w};
    unsigned int m = 0;
#pragma unroll
    for (int q = 0; q < 16; ++q) m |= (vs[q] != 0) ? (1u << q) : 0u;
    adjm[(size_t)b * 256 + t] = (unsigned short)m;
    return;
  }

  if (b < 4112) {  // ---- W -> WT bf16 ([c][k]) ----
    const int k0 = (b - 4096) * 16;
    const float* sp = W + (size_t)k0 * 256 + w * 1024 + lane * 4;
    int* dp = buf + w * 1024 + lane * 4;
#pragma unroll
    for (int r = 0; r < 4; ++r) gl16(sp + r * 256, dp + r * 256);
    __syncthreads();
    const float* wl = (const float*)buf;
    bf16x8 o0, o1;
#pragma unroll
    for (int k = 0; k < 8; ++k) o0[k] = (__bf16)wl[k * 256 + t];
#pragma unroll
    for (int k = 0; k < 8; ++k) o1[k] = (__bf16)wl[(8 + k) * 256 + t];
    __bf16* op = WT + (size_t)t * 256 + k0;
    *(bf16x8*)op = o0;
    *(bf16x8*)(op + 8) = o1;
    return;
  }

  // ---- x -> xb bf16 (row-major) ----
  const int bi = b - 4112;
  const float4* x4 = (const float4*)x;
#pragma unroll
  for (int it = 0; it < 4; ++it) {
    int g = it * 65536 + bi * 256 + t;   // float4 index, 256K total
    float4 f = x4[g];
    bf16x4 o = {(__bf16)f.x, (__bf16)f.y, (__bf16)f.z, (__bf16)f.w};
    *(bf16x4*)(xb + (size_t)g * 4) = o;
  }
}

// ---------------- Kernel 1: h = xb@W (MFMA) + scalars + hTf ----------------
// grid 256: it = b&63 (64-row tile), hh = b>>6. 256 threads = 4 waves.
__global__ __launch_bounds__(256, 2) void gat_prep(
    const __bf16* __restrict__ xb, const __bf16* __restrict__ WT,
    const float* __restrict__ a1, const float* __restrict__ a2,
    __bf16* __restrict__ hTf, float* __restrict__ siT, float2* __restrict__ vv2T,
    float* __restrict__ sjm) {
  // LDS: A-frags [0,32768) slot ((mt*8+kw)<<10), B-frags [32768,65536).
  // epilogue alias: hl f32[64][68] @0, sjb f32[64] @20480
  __shared__ __align__(16) char plds[65536];
  const int b = blockIdx.x, t = threadIdx.x;
  const int it = b & 63, hh = b >> 6;
  const int i0 = it * 64, c0 = hh * 64;
  const int w = t >> 6, lane = t & 63, quad = lane >> 4, l16 = lane & 15;

  // stage full-K fragments: wave w = A subtile mt=w (16 rows) + B subtile nt=w.
  const __bf16* asrc = xb + ((size_t)(i0 + w * 16 + l16) << 8) + quad * 8;
  const __bf16* bsrc = WT + ((size_t)(c0 + w * 16 + l16) << 8) + quad * 8;
#pragma unroll
  for (int kw = 0; kw < 8; ++kw) {
    gl16(asrc + kw * 32, plds + (((w * 8 + kw) << 10) + (lane << 4)));
    gl16(bsrc + kw * 32, plds + 32768 + (((w * 8 + kw) << 10) + (lane << 4)));
  }

  float a1v[4], a2v[4];
#pragma unroll
  for (int nt = 0; nt < 4; ++nt) {
    a1v[nt] = a1[nt * 16 + l16];
    a2v[nt] = a2[nt * 16 + l16];
  }
  __syncthreads();   // fragments staged

  floatx4 zv = {0.f, 0.f, 0.f, 0.f};
  floatx4 acc[4] = {zv, zv, zv, zv};
#pragma unroll
  for (int kw = 0; kw < 8; ++kw) {
    bf16x8 af = *(const bf16x8*)(plds + (((w * 8 + kw) << 10) + (lane << 4)));
#pragma unroll
    for (int nt = 0; nt < 4; ++nt) {
      bf16x8 bfr = *(const bf16x8*)(plds + 32768 + (((nt * 8 + kw) << 10) + (lane << 4)));
      acc[nt] = __builtin_amdgcn_mfma_f32_16x16x32_bf16(af, bfr, acc[nt], 0, 0, 0);
    }
  }
  __syncthreads();   // all LDS reads done; reuse plds for epilogue

  // C layout: row = w*16 + quad*4 + reg, col = nt*16 + l16
  float* hl = (float*)plds;              // [64][68]
  float* sjb = (float*)(plds + 20480);   // [64]
#pragma unroll
  for (int reg = 0; reg < 4; ++reg) {
    const int row = w * 16 + quad * 4 + reg;
#pragma unroll
    for (int nt = 0; nt < 4; ++nt) hl[row * 68 + nt * 16 + l16] = acc[nt][reg];
    float s1 = acc[0][reg] * a1v[0] + acc[1][reg] * a1v[1] +
               acc[2][reg] * a1v[2] + acc[3][reg] * a1v[3];
    float s2 = acc[0][reg] * a2v[0] + acc[1][reg] * a2v[1] +
               acc[2][reg] * a2v[2] + acc[3][reg] * a2v[3];
#pragma unroll
    for (int off = 1; off < 16; off <<= 1) {
      s1 += __shfl_xor(s1, off);
      s2 += __shfl_xor(s2, off);
    }
    if (l16 == 0) {
      siT[hh * NN + i0 + row] = s1 * LOG2E;
      float sjs = s2 * LOG2E;
      vv2T[hh * NN + i0 + row] =
          make_float2(__builtin_amdgcn_exp2f(sjs), __builtin_amdgcn_exp2f(0.2f * sjs));
      sjb[row] = sjs;
    }
  }
  __syncthreads();

  if (t < 64) {  // block sj-max partial (64 tiles -> sjm[64][4])
    float v = sjb[t];
#pragma unroll
    for (int off = 1; off < 64; off <<= 1) v = fmaxf(v, __shfl_xor(v, off));
    if (t == 0) sjm[it * 4 + hh] = v;
  }

  // fragment-major hTf: 2 chunks of 32 j; lane frag hT[d=nt2*16+l16][j=quad*8..+7]
  const int nt2 = t >> 6;
#pragma unroll
  for (int ch = 0; ch < 2; ++ch) {
    bf16x8 h0;
#pragma unroll
    for (int jj = 0; jj < 8; ++jj)
      h0[jj] = (__bf16)hl[(ch * 32 + quad * 8 + jj) * 68 + nt2 * 16 + l16];
    *(bf16x8*)((char*)hTf +
               ((((size_t)hh * 128 + it * 2 + ch) * 4 + nt2) << 10) + (lane << 4)) = h0;
  }
}

// ---------------- Kernel 2: masked softmax + PV (MFMA), direct out ----------------
// grid (128 i-tiles of 32 rows, 4 heads), 256 threads = 4 waves;
// wave w owns j-offset w*64 within each 256-j window; 16 windows cover all j.
__global__ __launch_bounds__(256, 2) void gat_attn(
    const __bf16* __restrict__ hTf, const float* __restrict__ siT,
    const float2* __restrict__ vv2T, const float* __restrict__ sjm,
    const unsigned int* __restrict__ adjw, float* __restrict__ out) {
  // LDS: hT buf0 [0,32768) | hT buf1 [32768,65536)
  // epilogue alias: accs f32[2][32][68] @0 (17408 B), lsum f32[2][32] @17408
  __shared__ __align__(16) char lds[65536];
  const int t = threadIdx.x;
  const int w = t >> 6, lane = t & 63, quad = lane >> 4, l16 = lane & 15;
  const int i0 = blockIdx.x * 32, hh = blockIdx.y;

  // staging source: this wave's first chunk (chunk = 32 j = 4 KB), + lane*16
  const char* hsrc = (const char*)hTf + (((size_t)hh * 128 + w * 2) << 12) + (lane << 4);
  const float2* vw = vv2T + (size_t)hh * NN + w * 64;

  const unsigned int* mp[2];
#pragma unroll
  for (int mt = 0; mt < 2; ++mt)
    mp[mt] = adjw + (size_t)(i0 + mt * 16 + l16) * 128 + w * 2;

  // ---- prefetch window 0: masks + vv2 (regs), hT (LDS buf0) ----
  uint2 mc[2], mn[2];
  float4 qc[2][4], qn[2][4];
#pragma unroll
  for (int mt = 0; mt < 2; ++mt) mc[mt] = *(const uint2*)mp[mt];
#pragma unroll
  for (int k = 0; k < 2; ++k) {
    const float4* qp = (const float4*)(vw + k * 32 + quad * 8);
#pragma unroll
    for (int c = 0; c < 4; ++c) qc[k][c] = qp[c];
  }
#pragma unroll
  for (int k = 0; k < 2; ++k)
#pragma unroll
    for (int nt = 0; nt < 4; ++nt)
      gl16(hsrc + ((k * 4 + nt) << 10),
           lds + (((w * 8 + k * 4 + nt) << 10) + (lane << 4)));

  // ---- per-row constants (overlaps staging); 64 sjm partials ----
  float vv = sjm[lane * 4 + hh];
#pragma unroll
  for (int off = 1; off < 64; off <<= 1) vv = fmaxf(vv, __shfl_xor(vv, off));
  float u[2], u2[2];
#pragma unroll
  for (int mt = 0; mt < 2; ++mt) {
    float sis = siT[hh * NN + i0 + mt * 16 + l16];
    float tt = sis + vv;
    float m = fmaxf(tt, 0.2f * tt);   // leaky monotone -> valid row-max upper bound
    u[mt] = __builtin_amdgcn_exp2f(sis - m);
    u2[mt] = __builtin_amdgcn_exp2f(0.2f * sis - m);
  }

  bf16x8 ones;
#pragma unroll
  for (int ii = 0; ii < 8; ++ii) ones[ii] = (__bf16)1.0f;

  floatx4 zv = {0.f, 0.f, 0.f, 0.f};
  floatx4 acc[2][4], lacc[2];
#pragma unroll
  for (int mt = 0; mt < 2; ++mt) {
    lacc[mt] = zv;
#pragma unroll
    for (int nt = 0; nt < 4; ++nt) acc[mt][nt] = zv;
  }

  __syncthreads();   // window 0 staged

  for (int win = 0; win < 16; ++win) {
    const int p = win & 1;
    const char* hb = lds + p * 32768;

    if (win + 1 < 16) {  // prefetch next window: regs first, then LDS staging
#pragma unroll
      for (int mt = 0; mt < 2; ++mt)
        mn[mt] = *(const uint2*)(mp[mt] + (win + 1) * 8);
#pragma unroll
      for (int k = 0; k < 2; ++k) {
        const float4* qp = (const float4*)(vw + (win + 1) * 256 + k * 32 + quad * 8);
#pragma unroll
        for (int c = 0; c < 4; ++c) qn[k][c] = qp[c];
      }
      char* hbn = lds + (p ^ 1) * 32768;
      const char* hs = hsrc + (win + 1) * 32768;
#pragma unroll
      for (int k = 0; k < 2; ++k)
#pragma unroll
        for (int nt = 0; nt < 4; ++nt)
          gl16(hs + ((k * 4 + nt) << 10),
               hbn + (((w * 8 + k * 4 + nt) << 10) + (lane << 4)));
    }

#pragma unroll
    for (int k = 0; k < 2; ++k) {
      bf16x8 bfr[4];
#pragma unroll
      for (int nt = 0; nt < 4; ++nt)
        bfr[nt] = *(const bf16x8*)(hb + ((w * 8 + k * 4 + nt) << 10) + (lane << 4));
#pragma unroll
      for (int mt = 0; mt < 2; ++mt) {
        unsigned int m8 = (k ? mc[mt].y : mc[mt].x) >> (quad * 8);
        bf16x8 af;
#pragma unroll
        for (int c = 0; c < 4; ++c) {
          float p0 = fmaxf(u[mt] * qc[k][c].x, u2[mt] * qc[k][c].y);
          float p1 = fmaxf(u[mt] * qc[k][c].z, u2[mt] * qc[k][c].w);
          // sign-extended 1-bit extract -> bitwise AND (2 VALU, no cmp/cndmask)
          int b0 = ((int)(m8 << (31 - 2 * c))) >> 31;
          int b1 = ((int)(m8 << (30 - 2 * c))) >> 31;
          af[2 * c]     = (__bf16)__uint_as_float(__float_as_uint(p0) & (unsigned)b0);
          af[2 * c + 1] = (__bf16)__uint_as_float(__float_as_uint(p1) & (unsigned)b1);
        }
#pragma unroll
        for (int nt = 0; nt < 4; ++nt)
          acc[mt][nt] = __builtin_amdgcn_mfma_f32_16x16x32_bf16(af, bfr[nt],
                                                                acc[mt][nt], 0, 0, 0);
        lacc[mt] = __builtin_amdgcn_mfma_f32_16x16x32_bf16(af, ones, lacc[mt], 0, 0, 0);
      }
    }
#pragma unroll
    for (int mt = 0; mt < 2; ++mt) mc[mt] = mn[mt];
#pragma unroll
    for (int k = 0; k < 2; ++k)
#pragma unroll
      for (int c = 0; c < 4; ++c) qc[k][c] = qn[k][c];
    __syncthreads();
  }

  // epilogue: combine the 4 j-offset waves in LDS (aliases dead staging bufs)
  float* accs = (float*)lds;             // [2][32][68]
  float* lsum = (float*)(lds + 17408);   // [2][32]
  // C layout: row = mt*16 + quad*4 + reg, col = nt*16 + l16
  if (w < 2) {
#pragma unroll
    for (int mt = 0; mt < 2; ++mt)
#pragma unroll
      for (int reg = 0; reg < 4; ++reg) {
        int row = mt * 16 + quad * 4 + reg;
        float* ap = accs + (w * 32 + row) * 68;
#pragma unroll
        for (int nt = 0; nt < 4; ++nt)
          ap[nt * 16 + l16] = acc[mt][nt][reg];
        if (l16 == 0) lsum[w * 32 + row] = lacc[mt][reg];
      }
  }
  __syncthreads();
  if (w >= 2) {
    const int bb = w - 2;
#pragma unroll
    for (int mt = 0; mt < 2; ++mt)
#pragma unroll
      for (int reg = 0; reg < 4; ++reg) {
        int row = mt * 16 + quad * 4 + reg;
        float* ap = accs + (bb * 32 + row) * 68;
#pragma unroll
        for (int nt = 0; nt < 4; ++nt)
          ap[nt * 16 + l16] += acc[mt][nt][reg];
        if (l16 == 0) lsum[bb * 32 + row] += lacc[mt][reg];
      }
  }
  __syncthreads();

  // normalize + direct out: r = t>>3 (32 rows), c = (t&7)*8 (8 cols per thread)
  const int r = t >> 3, c = (t & 7) * 8;
  float l = lsum[r] + lsum[32 + r];
  float inv = 1.0f / l;
  float o[8];
#pragma unroll
  for (int k = 0; k < 8; ++k)
    o[k] = (accs[r * 68 + c + k] + accs[(32 + r) * 68 + c + k]) * inv;
  float* op = out + (size_t)(i0 + r) * 256 + hh * 64 + c;
  *(float4*)op = make_float4(o[0], o[1], o[2], o[3]);
  *(float4*)(op + 4) = make_float4(o[4], o[5], o[6], o[7]);
}

extern "C" void kernel_launch(void* const* d_in, const int* in_sizes, int n_in,
                              void* d_out, int out_size, void* d_ws, size_t ws_size,
                              hipStream_t stream) {
  const float* x  = (const float*)d_in[0];
  const int*   adj = (const int*)d_in[1];
  const float* W  = (const float*)d_in[2];
  const float* a1 = (const float*)d_in[3];
  const float* a2 = (const float*)d_in[4];
  float* out = (float*)d_out;
  char* ws = (char*)d_ws;

  // ws layout (bytes):
  //   hTf  bf16   [4][128][4][1024B] @ 0   (2 MiB, fragment-major)
  //   siT  f32    [4][4096]     @ 2097152  (64 KiB)
  //   vv2T f32x2  [4][4096]     @ 2162688  (128 KiB)
  //   sjm  f32    [64][4]       @ 2293760  (1 KiB)
  //   adjb u16    [4096][256]   @ 2297856  (2 MiB bitmask)
  //   xb   bf16   [4096][256]   @ 4395008  (2 MiB)
  //   WT   bf16   [256][256]    @ 6492160  (128 KiB)
  __bf16* hTf  = (__bf16*)ws;
  float*  siT  = (float*)(ws + 2097152);
  float2* vv2T = (float2*)(ws + 2162688);
  float*  sjm  = (float*)(ws + 2293760);
  unsigned short* adjb = (unsigned short*)(ws + 2297856);
  __bf16* xb   = (__bf16*)(ws + 4395008);
  __bf16* WT   = (__bf16*)(ws + 6492160);

  gat_pack<<<4368, 256, 0, stream>>>(adj, x, W, adjb, xb, WT);
  gat_prep<<<256, 256, 0, stream>>>(xb, WT, a1, a2, hTf, siT, vv2T, sjm);
  gat_attn<<<dim3(128, 4), 256, 0, stream>>>(hTf, siT, vv2T, sjm,
                                             (const unsigned int*)adjb, out);
}